// Round 15
// baseline (177.466 us; speedup 1.0000x reference)
//
#include <hip/hip_runtime.h>
#include <stdint.h>

#define MDIM 2048
#define KDIM 4096
#define NDIM 8192
#define NG   32            // K / GROUP_SIZE
#define QROW 2048          // int32 per qweight row
#define NT2  64            // K-tiles of BK=64
#define LSTR 36            // fused-fallback LDS row stride
#define BUFH 32768         // f16 per buffer: A[256][64] + B[256][64]

typedef __attribute__((ext_vector_type(4)))  float    f32x4;
typedef __attribute__((ext_vector_type(16))) float    f32x16;
typedef __attribute__((ext_vector_type(2)))  _Float16 f16x2;
typedef __attribute__((ext_vector_type(8)))  _Float16 f16x8;
typedef __attribute__((ext_vector_type(4)))  int      i32x4;

#define CVT2(a,b) __builtin_bit_cast(f16x2, __builtin_amdgcn_cvt_pkrtz((a),(b)))
#define BCU(x)    __builtin_bit_cast(unsigned, (x))
#define BCH2(x)   __builtin_bit_cast(f16x2, (x))
#define MFMA16(A,B,C) __builtin_amdgcn_mfma_f32_16x16x32_f16((A),(B),(C),0,0,0)
#define MFMA32(A,B,C) __builtin_amdgcn_mfma_f32_32x32x16_f16((A),(B),(C),0,0,0)
#define LDSREAD(DST, OFF) __builtin_memcpy(&(DST), &lds[(OFF)], 16)

__device__ __forceinline__ void gload_lds16(const void* g, void* l) {
  __builtin_amdgcn_global_load_lds(
      (const __attribute__((address_space(1))) void*)g,
      (__attribute__((address_space(3))) void*)l, 16, 0, 0);
}

// dequant 4 int32 (8 weights, identity k-order) -> 8 fp16 (verified r3..r14)
__device__ __forceinline__ uint4 dequant8(i32x4 q, float sf, float zf) {
  const _Float16 sh = (_Float16)sf;
  const _Float16 bh = (_Float16)(-zf * sf);
  const f16x2 s2 = {sh, sh}, b2 = {bh, bh};
  const f16x2 k2 = {(_Float16)1024.0f, (_Float16)1024.0f};
  uint4 r;
#define DQE(QV, DST) do {                                                   \
    unsigned Bb_ = (unsigned)(QV) & 0xFFu;                                  \
    unsigned bits_ = ((Bb_ | (Bb_ << 12)) & 0x000F000Fu) | 0x64006400u;     \
    DST = BCU((f16x2)((BCH2(bits_) - k2) * s2 + b2));                       \
  } while (0)
  DQE(q.x, r.x); DQE(q.y, r.y); DQE(q.z, r.z); DQE(q.w, r.w);
#undef DQE
  return r;
}

// ============ pass 1a: W dequant -> f16 [N][K] in ws ============
__global__ __launch_bounds__(256) void dequant_w_kernel(
    const int* __restrict__ qw, const float* __restrict__ scales,
    const float* __restrict__ zeros, _Float16* __restrict__ Wf)
{
  const size_t total = (size_t)NDIM * (KDIM / 8);
  for (size_t t = (size_t)blockIdx.x * blockDim.x + threadIdx.x; t < total;
       t += (size_t)gridDim.x * blockDim.x) {
    i32x4 q;
    __builtin_memcpy(&q, qw + 4 * t, 16);
    const int n = (int)(t >> 9);
    const int k = (int)((t & 511) << 3);
    const int g = k >> 7;
    uint4 w = dequant8(q, scales[n * NG + g], zeros[n * NG + g]);
    __builtin_memcpy(Wf + (size_t)n * KDIM + k, &w, 16);
  }
}

// ============ pass 1b: A f32 -> f16 [M][K] in ws ============
__global__ __launch_bounds__(256) void conv_a_kernel(
    const float* __restrict__ A, _Float16* __restrict__ Af)
{
  const size_t total = (size_t)MDIM * (KDIM / 8);
  for (size_t t = (size_t)blockIdx.x * blockDim.x + threadIdx.x; t < total;
       t += (size_t)gridDim.x * blockDim.x) {
    f32x4 v0, v1;
    __builtin_memcpy(&v0, A + 8 * t,     16);
    __builtin_memcpy(&v1, A + 8 * t + 4, 16);
    uint4 h;
    h.x = BCU(CVT2(v0.x, v0.y));
    h.y = BCU(CVT2(v0.z, v0.w));
    h.z = BCU(CVT2(v1.x, v1.y));
    h.w = BCU(CVT2(v1.z, v1.w));
    __builtin_memcpy(Af + 8 * t, &h, 16);
  }
}

// ============ pass 2: f16 GEMM, 256x256, BK=64, 8 waves, 32x32x16 MFMA ============
// r14 pipeline skeleton VERBATIM (2 x 64KB bufs, depth-2, vmcnt(8), staging
// swizzle schunk=(t&7)^((t>>3)&7), ISSUE in P3 after barrier). Changed: MFMA
// shape 16x16x32 -> 32x32x16_f16 (2178 vs 1955 TF ceiling, half the instrs).
// Wave tile 128x64 = 4m x 2n frags of 32x32, acc = 8 x f32x16 (128 VGPRs).
// A frag: row=lane&31, k=(lane>>5)*8+e; B frag: col=lane&31, same k.
// Read chunk = (2*ks + (lane>>5)) ^ ((lane&31)&7) -> 2-way per 16-lane
// group = conflict-free (same mechanism as r14's measured 0 conflicts).
__global__ __launch_bounds__(512) void gemm_f16_kernel(
    const _Float16* __restrict__ Af,   // [M][K]
    const _Float16* __restrict__ Wf,   // [N][K]
    const float* __restrict__ bias,    // [N]
    float* __restrict__ out)           // [M][N] f32
{
  __shared__ __align__(16) _Float16 lds[2 * BUFH];   // 128 KB

  const int tid  = threadIdx.x;
  const int wave = tid >> 6;
  const int lane = tid & 63;
  const int n0 = blockIdx.x << 8;
  const int m0 = blockIdx.y << 8;
  const int wm = (wave >> 2) << 7;   // 0 or 128
  const int wn = (wave & 3) << 6;    // 0,64,128,192

  f32x16 acc[4][2] = {};   // [m-frag][n-frag]

  // ---- staging (r14 verbatim, verified) ----
  const int srow   = tid >> 3;                      // 0..63
  const int schunk = (tid & 7) ^ ((tid >> 3) & 7);
  const _Float16* aU0 = Af + (size_t)(m0 + srow) * KDIM + schunk * 8;
  const _Float16* aU1 = aU0 + (size_t)64 * KDIM;
  const _Float16* aU2 = aU0 + (size_t)128 * KDIM;
  const _Float16* aU3 = aU0 + (size_t)192 * KDIM;
  const _Float16* bU0 = Wf + (size_t)(n0 + srow) * KDIM + schunk * 8;
  const _Float16* bU1 = bU0 + (size_t)64 * KDIM;
  const _Float16* bU2 = bU0 + (size_t)128 * KDIM;
  const _Float16* bU3 = bU0 + (size_t)192 * KDIM;

#define ISSUE(T) do {                                                  \
    _Float16* d_ = &lds[((T) & 1) * BUFH + (wave << 9)];               \
    const size_t ko_ = (size_t)(T) << 6;                               \
    gload_lds16(aU0 + ko_, d_);                                        \
    gload_lds16(aU1 + ko_, d_ + 4096);                                 \
    gload_lds16(aU2 + ko_, d_ + 8192);                                 \
    gload_lds16(aU3 + ko_, d_ + 12288);                                \
    gload_lds16(bU0 + ko_, d_ + 16384);                                \
    gload_lds16(bU1 + ko_, d_ + 20480);                                \
    gload_lds16(bU2 + ko_, d_ + 24576);                                \
    gload_lds16(bU3 + ko_, d_ + 28672);                                \
  } while (0)

  // ---- 32x32 fragment read offsets ----
  // A frag (m-frag i, k-step ks): row = wm + 32i + (lane&31),
  //   chunk = (2*ks + (lane>>5)) ^ (row&7); f16 off = row*64 + chunk*8.
  const int fr32 = lane & 31;
  const int h2   = lane >> 5;           // 0 or 1
  const int sw8  = fr32 & 7;
  int raOff[4], rbOff[2], ckk[4];
#pragma unroll
  for (int i = 0; i < 4; ++i) raOff[i] = (wm + 32 * i + fr32) * 64;
#pragma unroll
  for (int j = 0; j < 2; ++j) rbOff[j] = 16384 + (wn + 32 * j + fr32) * 64;
#pragma unroll
  for (int ks = 0; ks < 4; ++ks) ckk[ks] = ((2 * ks + h2) ^ sw8) << 3;

  // tail compute (no staging)
#define COMPUTE(T) do {                                                \
    const int bb_ = ((T) & 1) * BUFH;                                  \
    f16x8 b_[2][4];                                                    \
    _Pragma("unroll")                                                  \
    for (int j = 0; j < 2; ++j)                                        \
      _Pragma("unroll")                                                \
      for (int ks = 0; ks < 4; ++ks)                                   \
        LDSREAD(b_[j][ks], bb_ + rbOff[j] + ckk[ks]);                  \
    _Pragma("unroll")                                                  \
    for (int i = 0; i < 4; ++i) {                                      \
      _Pragma("unroll")                                                \
      for (int ks = 0; ks < 4; ++ks) {                                 \
        f16x8 a_;                                                      \
        LDSREAD(a_, bb_ + raOff[i] + ckk[ks]);                         \
        acc[i][0] = MFMA32(a_, b_[0][ks], acc[i][0]);                  \
        acc[i][1] = MFMA32(a_, b_[1][ks], acc[i][1]);                  \
      }                                                                \
    }                                                                  \
  } while (0)

  // 8-MFMA phase body for m-frag I (A frags aK0..aK3 in regs)
#define PH_MFMA(I) do {                                                \
    __builtin_amdgcn_s_setprio(1);                                     \
    acc[I][0] = MFMA32(aK0, bf[0][0], acc[I][0]);                      \
    acc[I][1] = MFMA32(aK0, bf[1][0], acc[I][1]);                      \
    acc[I][0] = MFMA32(aK1, bf[0][1], acc[I][0]);                      \
    acc[I][1] = MFMA32(aK1, bf[1][1], acc[I][1]);                      \
    acc[I][0] = MFMA32(aK2, bf[0][2], acc[I][0]);                      \
    acc[I][1] = MFMA32(aK2, bf[1][2], acc[I][1]);                      \
    acc[I][0] = MFMA32(aK3, bf[0][3], acc[I][0]);                      \
    acc[I][1] = MFMA32(aK3, bf[1][3], acc[I][1]);                      \
    __builtin_amdgcn_s_setprio(0);                                     \
  } while (0)

#define RD_A(I)                                                        \
    LDSREAD(aK0, bb + raOff[I] + ckk[0]);                              \
    LDSREAD(aK1, bb + raOff[I] + ckk[1]);                              \
    LDSREAD(aK2, bb + raOff[I] + ckk[2]);                              \
    LDSREAD(aK3, bb + raOff[I] + ckk[3]);

  // prologue: 2 tiles in flight (16 loads/thread)
  ISSUE(0); ISSUE(1);

#pragma clang loop unroll(disable)
  for (int t = 0; t < NT2 - 2; ++t) {
    asm volatile("s_waitcnt vmcnt(8)" ::: "memory");   // tile t landed; t+1 in flight
    __builtin_amdgcn_s_barrier();
    const int bb = (t & 1) * BUFH;

    f16x8 bf[2][4], aK0, aK1, aK2, aK3;

    // ---- P0: all B frags + A m-frag 0 -> 8 MFMA ----
#pragma unroll
    for (int j = 0; j < 2; ++j)
#pragma unroll
      for (int ks = 0; ks < 4; ++ks)
        LDSREAD(bf[j][ks], bb + rbOff[j] + ckk[ks]);
    RD_A(0)
    __builtin_amdgcn_s_barrier();
    PH_MFMA(0);

    // ---- P1: A m-frag 1 -> 8 MFMA ----
    RD_A(1)
    __builtin_amdgcn_s_barrier();
    PH_MFMA(1);

    // ---- P2: A m-frag 2 -> 8 MFMA ----
    RD_A(2)
    __builtin_amdgcn_s_barrier();
    PH_MFMA(2);

    // ---- P3: A m-frag 3 -> barrier -> ISSUE(t+2) -> 8 MFMA ----
    RD_A(3)
    __builtin_amdgcn_s_barrier();
    ISSUE(t + 2);
    PH_MFMA(3);
  }

  // tail
  asm volatile("s_waitcnt vmcnt(8)" ::: "memory");
  __builtin_amdgcn_s_barrier();
  COMPUTE(NT2 - 2);
  asm volatile("s_waitcnt vmcnt(0)" ::: "memory");
  __builtin_amdgcn_s_barrier();
  COMPUTE(NT2 - 1);

#undef ISSUE
#undef COMPUTE
#undef PH_MFMA
#undef RD_A

  // epilogue: 32x32 C/D layout: col = lane&31,
  // row = (reg&3) + 8*(reg>>2) + 4*(lane>>5)   [m74/m101, dtype-indep]
  const int cc = lane & 31;
  const int rbase = 4 * (lane >> 5);
#pragma unroll
  for (int i = 0; i < 4; ++i) {
#pragma unroll
    for (int j = 0; j < 2; ++j) {
      const int n = n0 + wn + 32 * j + cc;
      const float bv = bias[n];
#pragma unroll
      for (int reg = 0; reg < 16; ++reg) {
        const int mrow = m0 + wm + 32 * i + (reg & 3) + 8 * (reg >> 2) + rbase;
        out[(size_t)mrow * NDIM + n] = acc[i][j][reg] + bv;
      }
    }
  }
}

// ============ fused fallback (round-6 kernel, verified PASS) ============
__global__ __launch_bounds__(256, 4) void qlin_fused_kernel(
    const float* __restrict__ A, const int* __restrict__ qw,
    const float* __restrict__ scales, const float* __restrict__ zeros,
    const float* __restrict__ bias, float* __restrict__ out)
{
  __shared__ _Float16 As[2][128 * LSTR];
  __shared__ _Float16 Bs[2][128 * LSTR];

  const int tid  = threadIdx.x;
  const int wave = tid >> 6;
  const int lane = tid & 63;
  const int n0 = blockIdx.x << 7;
  const int m0 = blockIdx.y << 7;
  const int wm = (wave >> 1) << 6;
  const int wn = (wave & 1) << 6;

  f32x4 acc[4][4] = {};

  const int r4 = tid >> 2;
  const int c4 = tid & 3;

  const float* aP0 = A + (size_t)(m0 + r4) * KDIM + c4 * 8;
  const float* aP1 = aP0 + (size_t)64 * KDIM;
  const int*   qP0 = qw + (size_t)(n0 + r4) * QROW + c4 * 4;
  const int*   qP1 = qP0 + (size_t)64 * QROW;
  const float* sP0 = scales + (size_t)(n0 + r4) * NG;
  const float* zP0 = zeros  + (size_t)(n0 + r4) * NG;
  const float* sP1 = sP0 + (size_t)64 * NG;
  const float* zP1 = zP0 + (size_t)64 * NG;

  const int aD0 = r4 * LSTR + c4 * 8;
  const int aD1 = (r4 + 64) * LSTR + c4 * 8;

  const int fr = lane & 15;
  const int k0 = (lane >> 4) * 8;
  const int ra0 = (wm +  0 + fr) * LSTR + k0;
  const int ra1 = (wm + 16 + fr) * LSTR + k0;
  const int ra2 = (wm + 32 + fr) * LSTR + k0;
  const int ra3 = (wm + 48 + fr) * LSTR + k0;
  const int rb0 = (wn +  0 + fr) * LSTR + k0;
  const int rb1 = (wn + 16 + fr) * LSTR + k0;
  const int rb2 = (wn + 32 + fr) * LSTR + k0;
  const int rb3 = (wn + 48 + fr) * LSTR + k0;

  f32x4 pa0, pa1, pa2, pa3;
  i32x4 pq0, pq1;
  float psf0, pzf0, psf1, pzf1;

#define ISSUE(KT) do {                                                        \
    __builtin_memcpy(&pa0, aP0 + (size_t)(KT) * 32,     16);                  \
    __builtin_memcpy(&pa1, aP0 + (size_t)(KT) * 32 + 4, 16);                  \
    __builtin_memcpy(&pa2, aP1 + (size_t)(KT) * 32,     16);                  \
    __builtin_memcpy(&pa3, aP1 + (size_t)(KT) * 32 + 4, 16);                  \
    __builtin_memcpy(&pq0, qP0 + (size_t)(KT) * 16, 16);                      \
    __builtin_memcpy(&pq1, qP1 + (size_t)(KT) * 16, 16);                      \
    const int g_ = (KT) >> 2;                                                 \
    psf0 = sP0[g_]; pzf0 = zP0[g_];                                           \
    psf1 = sP1[g_]; pzf1 = zP1[g_];                                           \
  } while (0)

#define STAGE(P) do {                                                         \
    uint4 aw0_;                                                               \
    aw0_.x = BCU(CVT2(pa0.x, pa0.y));                                         \
    aw0_.y = BCU(CVT2(pa0.z, pa0.w));                                         \
    aw0_.z = BCU(CVT2(pa1.x, pa1.y));                                         \
    aw0_.w = BCU(CVT2(pa1.z, pa1.w));                                         \
    __builtin_memcpy(&As[P][aD0], &aw0_, 16);                                 \
    uint4 aw1_;                                                               \
    aw1_.x = BCU(CVT2(pa2.x, pa2.y));                                         \
    aw1_.y = BCU(CVT2(pa2.z, pa2.w));                                         \
    aw1_.z = BCU(CVT2(pa3.x, pa3.y));                                         \
    aw1_.w = BCU(CVT2(pa3.z, pa3.w));                                         \
    __builtin_memcpy(&As[P][aD1], &aw1_, 16);                                 \
    uint4 bw0_ = dequant8(pq0, psf0, pzf0);                                   \
    __builtin_memcpy(&Bs[P][aD0], &bw0_, 16);                                 \
    uint4 bw1_ = dequant8(pq1, psf1, pzf1);                                   \
    __builtin_memcpy(&Bs[P][aD1], &bw1_, 16);                                 \
  } while (0)

#define COMPUTE(P) do {                                                       \
    f16x8 af[4], bfr[4];                                                      \
    __builtin_memcpy(&af[0], &As[P][ra0], 16);                                \
    __builtin_memcpy(&af[1], &As[P][ra1], 16);                                \
    __builtin_memcpy(&af[2], &As[P][ra2], 16);                                \
    __builtin_memcpy(&af[3], &As[P][ra3], 16);                                \
    __builtin_memcpy(&bfr[0], &Bs[P][rb0], 16);                               \
    __builtin_memcpy(&bfr[1], &Bs[P][rb1], 16);                               \
    __builtin_memcpy(&bfr[2], &Bs[P][rb2], 16);                               \
    __builtin_memcpy(&bfr[3], &Bs[P][rb3], 16);                               \
    _Pragma("unroll")                                                         \
    for (int i = 0; i < 4; ++i)                                               \
      _Pragma("unroll")                                                       \
      for (int j = 0; j < 4; ++j)                                             \
        acc[i][j] = MFMA16(af[i], bfr[j], acc[i][j]);                         \
  } while (0)

  ISSUE(0);
  STAGE(0);
  __syncthreads();

#pragma clang loop unroll(disable)
  for (int kt = 0; kt < 127; ++kt) {
    const int p = kt & 1;
    ISSUE(kt + 1);
    COMPUTE(p);
    STAGE(p ^ 1);
    __syncthreads();
  }
  COMPUTE(1);

#undef ISSUE
#undef STAGE
#undef COMPUTE

  const int cr = (lane >> 4) << 2;
  const int cc = lane & 15;
#pragma unroll
  for (int j = 0; j < 4; ++j) {
    const int n = n0 + wn + j * 16 + cc;
    const float bv = bias[n];
#pragma unroll
    for (int i = 0; i < 4; ++i) {
      const int mrow = m0 + wm + i * 16 + cr;
#pragma unroll
      for (int r = 0; r < 4; ++r)
        out[(size_t)(mrow + r) * NDIM + n] = acc[i][j][r] + bv;
    }
  }
}

extern "C" void kernel_launch(void* const* d_in, const int* in_sizes, int n_in,
                              void* d_out, int out_size, void* d_ws, size_t ws_size,
                              hipStream_t stream) {
  const float* A      = (const float*)d_in[0];
  const int*   qwp    = (const int*)d_in[1];
  const float* scales = (const float*)d_in[2];
  const float* zerosp = (const float*)d_in[3];
  const float* biasp  = (const float*)d_in[4];
  float*       outp   = (float*)d_out;

  const size_t needW = (size_t)NDIM * KDIM * sizeof(_Float16);   // 64 MB
  const size_t needA = (size_t)MDIM * KDIM * sizeof(_Float16);   // 16 MB

  if (ws_size >= needW + needA) {
    _Float16* Wf = (_Float16*)d_ws;
    _Float16* Af = (_Float16*)((char*)d_ws + needW);
    dequant_w_kernel<<<2048, 256, 0, stream>>>(qwp, scales, zerosp, Wf);
    conv_a_kernel<<<2048, 256, 0, stream>>>(A, Af);
    dim3 grid(NDIM / 256, MDIM / 256);  // 32 x 8 = 256 blocks (1/CU)
    gemm_f16_kernel<<<grid, 512, 0, stream>>>(Af, Wf, biasp, outp);
  } else {
    dim3 grid(NDIM / 128, MDIM / 128);
    qlin_fused_kernel<<<grid, 256, 0, stream>>>(A, qwp, scales, zerosp, biasp, outp);
  }
}

// Round 16
// 155.596 us; speedup vs baseline: 1.1406x; 1.1406x over previous
//
#include <hip/hip_runtime.h>
#include <stdint.h>

#define MDIM 2048
#define KDIM 4096
#define NDIM 8192
#define NG   32            // K / GROUP_SIZE
#define QROW 2048          // int32 per qweight row
#define NT2  64            // K-tiles of BK=64
#define LSTR 36            // fused-fallback LDS row stride
#define BUFH 32768         // f16 per buffer: A[256][64] + B[256][64]

typedef __attribute__((ext_vector_type(4))) float    f32x4;
typedef __attribute__((ext_vector_type(2))) _Float16 f16x2;
typedef __attribute__((ext_vector_type(8))) _Float16 f16x8;
typedef __attribute__((ext_vector_type(4))) int      i32x4;

#define CVT2(a,b) __builtin_bit_cast(f16x2, __builtin_amdgcn_cvt_pkrtz((a),(b)))
#define BCU(x)    __builtin_bit_cast(unsigned, (x))
#define BCH2(x)   __builtin_bit_cast(f16x2, (x))
#define MFMA16(A,B,C) __builtin_amdgcn_mfma_f32_16x16x32_f16((A),(B),(C),0,0,0)
#define LDSREAD(DST, OFF) __builtin_memcpy(&(DST), &lds[(OFF)], 16)

__device__ __forceinline__ void gload_lds16(const void* g, void* l) {
  __builtin_amdgcn_global_load_lds(
      (const __attribute__((address_space(1))) void*)g,
      (__attribute__((address_space(3))) void*)l, 16, 0, 0);
}

// dequant 4 int32 (8 weights, identity k-order) -> 8 fp16 (verified r3..r15)
__device__ __forceinline__ uint4 dequant8(i32x4 q, float sf, float zf) {
  const _Float16 sh = (_Float16)sf;
  const _Float16 bh = (_Float16)(-zf * sf);
  const f16x2 s2 = {sh, sh}, b2 = {bh, bh};
  const f16x2 k2 = {(_Float16)1024.0f, (_Float16)1024.0f};
  uint4 r;
#define DQE(QV, DST) do {                                                   \
    unsigned Bb_ = (unsigned)(QV) & 0xFFu;                                  \
    unsigned bits_ = ((Bb_ | (Bb_ << 12)) & 0x000F000Fu) | 0x64006400u;     \
    DST = BCU((f16x2)((BCH2(bits_) - k2) * s2 + b2));                       \
  } while (0)
  DQE(q.x, r.x); DQE(q.y, r.y); DQE(q.z, r.z); DQE(q.w, r.w);
#undef DQE
  return r;
}

// ============ pass 1a: W dequant -> f16 [N][K] in ws ============
__global__ __launch_bounds__(256) void dequant_w_kernel(
    const int* __restrict__ qw, const float* __restrict__ scales,
    const float* __restrict__ zeros, _Float16* __restrict__ Wf)
{
  const size_t total = (size_t)NDIM * (KDIM / 8);
  for (size_t t = (size_t)blockIdx.x * blockDim.x + threadIdx.x; t < total;
       t += (size_t)gridDim.x * blockDim.x) {
    i32x4 q;
    __builtin_memcpy(&q, qw + 4 * t, 16);
    const int n = (int)(t >> 9);
    const int k = (int)((t & 511) << 3);
    const int g = k >> 7;
    uint4 w = dequant8(q, scales[n * NG + g], zeros[n * NG + g]);
    __builtin_memcpy(Wf + (size_t)n * KDIM + k, &w, 16);
  }
}

// ============ pass 1b: A f32 -> f16 [M][K] in ws ============
__global__ __launch_bounds__(256) void conv_a_kernel(
    const float* __restrict__ A, _Float16* __restrict__ Af)
{
  const size_t total = (size_t)MDIM * (KDIM / 8);
  for (size_t t = (size_t)blockIdx.x * blockDim.x + threadIdx.x; t < total;
       t += (size_t)gridDim.x * blockDim.x) {
    f32x4 v0, v1;
    __builtin_memcpy(&v0, A + 8 * t,     16);
    __builtin_memcpy(&v1, A + 8 * t + 4, 16);
    uint4 h;
    h.x = BCU(CVT2(v0.x, v0.y));
    h.y = BCU(CVT2(v0.z, v0.w));
    h.z = BCU(CVT2(v1.x, v1.y));
    h.w = BCU(CVT2(v1.z, v1.w));
    __builtin_memcpy(Af + 8 * t, &h, 16);
  }
}

// ============ pass 2: f16 GEMM, 256x256, BK=64, 8 waves, m201-style phases ============
// r14 skeleton (verified 0-conflict, PASS): 2 x 64KB bufs, staging swizzle
// schunk=(t&7)^((t>>3)&7), read chunk=(kk*4+h)^(fr&7), 16x16x32 MFMA.
// NEW (m201 port): staging spread 2 gloads/phase; counted vmcnt(2) gate
// (never drains); double-barrier phases {reads+stage | barrier | lgkmcnt(0) |
// setprio 16 MFMA setprio | barrier}.
// Staging assignment: iter t: P0/P1/P2 stage tile t+1 parts 2/3/4 (buf t^1,
// free since iter t-1 P3); P3 stages tile t+2 part 1 (buf t&1, after the
// mid-phase barrier = post-last-read; r8-r14-verified placement).
__global__ __launch_bounds__(512) void gemm_f16_kernel(
    const _Float16* __restrict__ Af,   // [M][K]
    const _Float16* __restrict__ Wf,   // [N][K]
    const float* __restrict__ bias,    // [N]
    float* __restrict__ out)           // [M][N] f32
{
  __shared__ __align__(16) _Float16 lds[2 * BUFH];   // 128 KB

  const int tid  = threadIdx.x;
  const int wave = tid >> 6;
  const int lane = tid & 63;
  const int n0 = blockIdx.x << 8;
  const int m0 = blockIdx.y << 8;
  const int wm = (wave >> 2) << 7;   // 0 or 128
  const int wn = (wave & 3) << 6;    // 0,64,128,192

  f32x4 acc[8][4] = {};

  // ---- staging (r14 verbatim) ----
  const int srow   = tid >> 3;                      // 0..63
  const int schunk = (tid & 7) ^ ((tid >> 3) & 7);
  const _Float16* aU0 = Af + (size_t)(m0 + srow) * KDIM + schunk * 8;
  const _Float16* aU1 = aU0 + (size_t)64 * KDIM;
  const _Float16* aU2 = aU0 + (size_t)128 * KDIM;
  const _Float16* aU3 = aU0 + (size_t)192 * KDIM;
  const _Float16* bU0 = Wf + (size_t)(n0 + srow) * KDIM + schunk * 8;
  const _Float16* bU1 = bU0 + (size_t)64 * KDIM;
  const _Float16* bU2 = bU0 + (size_t)128 * KDIM;
  const _Float16* bU3 = bU0 + (size_t)192 * KDIM;

  // part k of tile X (2 gloads each): p1={A rows 0-127}, p2={A 128-255},
  // p3={B 0-127}, p4={B 128-255}
#define STAGE_P1(X) do {                                               \
    _Float16* d_ = &lds[((X) & 1) * BUFH + (wave << 9)];               \
    const size_t ko_ = (size_t)(X) << 6;                               \
    gload_lds16(aU0 + ko_, d_);                                        \
    gload_lds16(aU1 + ko_, d_ + 4096);                                 \
  } while (0)
#define STAGE_P2(X) do {                                               \
    _Float16* d_ = &lds[((X) & 1) * BUFH + (wave << 9)];               \
    const size_t ko_ = (size_t)(X) << 6;                               \
    gload_lds16(aU2 + ko_, d_ + 8192);                                 \
    gload_lds16(aU3 + ko_, d_ + 12288);                                \
  } while (0)
#define STAGE_P3(X) do {                                               \
    _Float16* d_ = &lds[((X) & 1) * BUFH + (wave << 9)];               \
    const size_t ko_ = (size_t)(X) << 6;                               \
    gload_lds16(bU0 + ko_, d_ + 16384);                                \
    gload_lds16(bU1 + ko_, d_ + 20480);                                \
  } while (0)
#define STAGE_P4(X) do {                                               \
    _Float16* d_ = &lds[((X) & 1) * BUFH + (wave << 9)];               \
    const size_t ko_ = (size_t)(X) << 6;                               \
    gload_lds16(bU2 + ko_, d_ + 24576);                                \
    gload_lds16(bU3 + ko_, d_ + 28672);                                \
  } while (0)

  // ---- fragment read offsets (r14 verbatim; measured 0 conflicts) ----
  const int fr = lane & 15;
  const int h4 = lane >> 4;
  const int ck0 = (((0 + h4) ^ (fr & 7))) << 3;
  const int ck1 = (((4 + h4) ^ (fr & 7))) << 3;
  int raOff[8], rbOff[4];
#pragma unroll
  for (int i = 0; i < 8; ++i) raOff[i] = (wm + 16 * i + fr) * 64;
#pragma unroll
  for (int j = 0; j < 4; ++j) rbOff[j] = 16384 + (wn + 16 * j + fr) * 64;

  // tail compute (r14 verbatim, no staging)
#define COMPUTE(T) do {                                                \
    const int bb_ = ((T) & 1) * BUFH;                                  \
    f16x8 b0_[4], b1_[4];                                              \
    _Pragma("unroll")                                                  \
    for (int j = 0; j < 4; ++j) {                                      \
      LDSREAD(b0_[j], bb_ + rbOff[j] + ck0);                           \
      LDSREAD(b1_[j], bb_ + rbOff[j] + ck1);                           \
    }                                                                  \
    _Pragma("unroll")                                                  \
    for (int i = 0; i < 8; ++i) {                                      \
      f16x8 a0_, a1_;                                                  \
      LDSREAD(a0_, bb_ + raOff[i] + ck0);                              \
      LDSREAD(a1_, bb_ + raOff[i] + ck1);                              \
      _Pragma("unroll")                                                \
      for (int j = 0; j < 4; ++j)                                      \
        acc[i][j] = MFMA16(a0_, b0_[j], acc[i][j]);                    \
      _Pragma("unroll")                                                \
      for (int j = 0; j < 4; ++j)                                      \
        acc[i][j] = MFMA16(a1_, b1_[j], acc[i][j]);                    \
    }                                                                  \
  } while (0)

  // 16-MFMA phase body (r14 verbatim)
#define PH_MFMA(R) do {                                                \
    __builtin_amdgcn_s_setprio(1);                                     \
    _Pragma("unroll")                                                  \
    for (int j = 0; j < 4; ++j) {                                      \
      acc[(R)][j]     = MFMA16(aA0, bf0[j], acc[(R)][j]);              \
      acc[(R) + 1][j] = MFMA16(aB0, bf0[j], acc[(R) + 1][j]);          \
    }                                                                  \
    _Pragma("unroll")                                                  \
    for (int j = 0; j < 4; ++j) {                                      \
      acc[(R)][j]     = MFMA16(aA1, bf1[j], acc[(R)][j]);              \
      acc[(R) + 1][j] = MFMA16(aB1, bf1[j], acc[(R) + 1][j]);          \
    }                                                                  \
    __builtin_amdgcn_s_setprio(0);                                     \
  } while (0)

#define RD_A(I)                                                        \
    LDSREAD(aA0, bb + raOff[I] + ck0);                                 \
    LDSREAD(aA1, bb + raOff[I] + ck1);                                 \
    LDSREAD(aB0, bb + raOff[(I) + 1] + ck0);                           \
    LDSREAD(aB1, bb + raOff[(I) + 1] + ck1);

#define MIDSYNC                                                        \
    __builtin_amdgcn_s_barrier();                                      \
    asm volatile("s_waitcnt lgkmcnt(0)" ::: "memory");                 \
    __builtin_amdgcn_sched_barrier(0);

  // prologue: tile 0 fully + tile 1 part 1  (10 loads outstanding)
  STAGE_P1(0); STAGE_P2(0); STAGE_P3(0); STAGE_P4(0);
  STAGE_P1(1);

#pragma clang loop unroll(disable)
  for (int t = 0; t < NT2 - 2; ++t) {
    // gate: tile t fully landed (in-order drain; leaves only the 2 newest)
    asm volatile("s_waitcnt vmcnt(2)" ::: "memory");
    __builtin_amdgcn_s_barrier();
    const int bb = (t & 1) * BUFH;

    f16x8 bf0[4], bf1[4], aA0, aA1, aB0, aB1;

    // ---- P0: all B frags + A rows 0,1 | stage t+1 part2 ----
#pragma unroll
    for (int j = 0; j < 4; ++j) {
      LDSREAD(bf0[j], bb + rbOff[j] + ck0);
      LDSREAD(bf1[j], bb + rbOff[j] + ck1);
    }
    RD_A(0)
    STAGE_P2(t + 1);
    MIDSYNC
    PH_MFMA(0);
    __builtin_amdgcn_s_barrier();

    // ---- P1: A rows 2,3 | stage t+1 part3 ----
    RD_A(2)
    STAGE_P3(t + 1);
    MIDSYNC
    PH_MFMA(2);
    __builtin_amdgcn_s_barrier();

    // ---- P2: A rows 4,5 | stage t+1 part4 ----
    RD_A(4)
    STAGE_P4(t + 1);
    MIDSYNC
    PH_MFMA(4);
    __builtin_amdgcn_s_barrier();

    // ---- P3: A rows 6,7 | stage t+2 part1 AFTER mid-barrier ----
    RD_A(6)
    MIDSYNC
    STAGE_P1(t + 2);
    PH_MFMA(6);
    // iteration-end barrier is the next iter's top barrier
  }

  // tail: outstanding = NT2-2 p2,p3,p4 (6, oldest) + NT2-1 p1 (2)
  STAGE_P2(NT2 - 1); STAGE_P3(NT2 - 1); STAGE_P4(NT2 - 1);   // +6 -> 14
  asm volatile("s_waitcnt vmcnt(8)" ::: "memory");            // drain 6 oldest = NT2-2 done
  __builtin_amdgcn_s_barrier();
  COMPUTE(NT2 - 2);
  asm volatile("s_waitcnt vmcnt(0)" ::: "memory");
  __builtin_amdgcn_s_barrier();
  COMPUTE(NT2 - 1);

#undef STAGE_P1
#undef STAGE_P2
#undef STAGE_P3
#undef STAGE_P4
#undef COMPUTE
#undef PH_MFMA
#undef RD_A
#undef MIDSYNC

  // epilogue: C/D col = lane&15, row = (lane>>4)*4 + reg (r9-r14 verbatim)
  const int cr = (lane >> 4) << 2;
  const int cc = lane & 15;
#pragma unroll
  for (int j = 0; j < 4; ++j) {
    const int n = n0 + wn + j * 16 + cc;
    const float bv = bias[n];
#pragma unroll
    for (int i = 0; i < 8; ++i) {
      const int mrow = m0 + wm + i * 16 + cr;
#pragma unroll
      for (int r = 0; r < 4; ++r)
        out[(size_t)(mrow + r) * NDIM + n] = acc[i][j][r] + bv;
    }
  }
}

// ============ fused fallback (round-6 kernel, verified PASS) ============
__global__ __launch_bounds__(256, 4) void qlin_fused_kernel(
    const float* __restrict__ A, const int* __restrict__ qw,
    const float* __restrict__ scales, const float* __restrict__ zeros,
    const float* __restrict__ bias, float* __restrict__ out)
{
  __shared__ _Float16 As[2][128 * LSTR];
  __shared__ _Float16 Bs[2][128 * LSTR];

  const int tid  = threadIdx.x;
  const int wave = tid >> 6;
  const int lane = tid & 63;
  const int n0 = blockIdx.x << 7;
  const int m0 = blockIdx.y << 7;
  const int wm = (wave >> 1) << 6;
  const int wn = (wave & 1) << 6;

  f32x4 acc[4][4] = {};

  const int r4 = tid >> 2;
  const int c4 = tid & 3;

  const float* aP0 = A + (size_t)(m0 + r4) * KDIM + c4 * 8;
  const float* aP1 = aP0 + (size_t)64 * KDIM;
  const int*   qP0 = qw + (size_t)(n0 + r4) * QROW + c4 * 4;
  const int*   qP1 = qP0 + (size_t)64 * QROW;
  const float* sP0 = scales + (size_t)(n0 + r4) * NG;
  const float* zP0 = zeros  + (size_t)(n0 + r4) * NG;
  const float* sP1 = sP0 + (size_t)64 * NG;
  const float* zP1 = zP0 + (size_t)64 * NG;

  const int aD0 = r4 * LSTR + c4 * 8;
  const int aD1 = (r4 + 64) * LSTR + c4 * 8;

  const int fr = lane & 15;
  const int k0 = (lane >> 4) * 8;
  const int ra0 = (wm +  0 + fr) * LSTR + k0;
  const int ra1 = (wm + 16 + fr) * LSTR + k0;
  const int ra2 = (wm + 32 + fr) * LSTR + k0;
  const int ra3 = (wm + 48 + fr) * LSTR + k0;
  const int rb0 = (wn +  0 + fr) * LSTR + k0;
  const int rb1 = (wn + 16 + fr) * LSTR + k0;
  const int rb2 = (wn + 32 + fr) * LSTR + k0;
  const int rb3 = (wn + 48 + fr) * LSTR + k0;

  f32x4 pa0, pa1, pa2, pa3;
  i32x4 pq0, pq1;
  float psf0, pzf0, psf1, pzf1;

#define ISSUE(KT) do {                                                        \
    __builtin_memcpy(&pa0, aP0 + (size_t)(KT) * 32,     16);                  \
    __builtin_memcpy(&pa1, aP0 + (size_t)(KT) * 32 + 4, 16);                  \
    __builtin_memcpy(&pa2, aP1 + (size_t)(KT) * 32,     16);                  \
    __builtin_memcpy(&pa3, aP1 + (size_t)(KT) * 32 + 4, 16);                  \
    __builtin_memcpy(&pq0, qP0 + (size_t)(KT) * 16, 16);                      \
    __builtin_memcpy(&pq1, qP1 + (size_t)(KT) * 16, 16);                      \
    const int g_ = (KT) >> 2;                                                 \
    psf0 = sP0[g_]; pzf0 = zP0[g_];                                           \
    psf1 = sP1[g_]; pzf1 = zP1[g_];                                           \
  } while (0)

#define STAGE(P) do {                                                         \
    uint4 aw0_;                                                               \
    aw0_.x = BCU(CVT2(pa0.x, pa0.y));                                         \
    aw0_.y = BCU(CVT2(pa0.z, pa0.w));                                         \
    aw0_.z = BCU(CVT2(pa1.x, pa1.y));                                         \
    aw0_.w = BCU(CVT2(pa1.z, pa1.w));                                         \
    __builtin_memcpy(&As[P][aD0], &aw0_, 16);                                 \
    uint4 aw1_;                                                               \
    aw1_.x = BCU(CVT2(pa2.x, pa2.y));                                         \
    aw1_.y = BCU(CVT2(pa2.z, pa2.w));                                         \
    aw1_.z = BCU(CVT2(pa3.x, pa3.y));                                         \
    aw1_.w = BCU(CVT2(pa3.z, pa3.w));                                         \
    __builtin_memcpy(&As[P][aD1], &aw1_, 16);                                 \
    uint4 bw0_ = dequant8(pq0, psf0, pzf0);                                   \
    __builtin_memcpy(&Bs[P][aD0], &bw0_, 16);                                 \
    uint4 bw1_ = dequant8(pq1, psf1, pzf1);                                   \
    __builtin_memcpy(&Bs[P][aD1], &bw1_, 16);                                 \
  } while (0)

#define COMPUTE(P) do {                                                       \
    f16x8 af[4], bfr[4];                                                      \
    __builtin_memcpy(&af[0], &As[P][ra0], 16);                                \
    __builtin_memcpy(&af[1], &As[P][ra1], 16);                                \
    __builtin_memcpy(&af[2], &As[P][ra2], 16);                                \
    __builtin_memcpy(&af[3], &As[P][ra3], 16);                                \
    __builtin_memcpy(&bfr[0], &Bs[P][rb0], 16);                               \
    __builtin_memcpy(&bfr[1], &Bs[P][rb1], 16);                               \
    __builtin_memcpy(&bfr[2], &Bs[P][rb2], 16);                               \
    __builtin_memcpy(&bfr[3], &Bs[P][rb3], 16);                               \
    _Pragma("unroll")                                                         \
    for (int i = 0; i < 4; ++i)                                               \
      _Pragma("unroll")                                                       \
      for (int j = 0; j < 4; ++j)                                             \
        acc[i][j] = MFMA16(af[i], bfr[j], acc[i][j]);                         \
  } while (0)

  ISSUE(0);
  STAGE(0);
  __syncthreads();

#pragma clang loop unroll(disable)
  for (int kt = 0; kt < 127; ++kt) {
    const int p = kt & 1;
    ISSUE(kt + 1);
    COMPUTE(p);
    STAGE(p ^ 1);
    __syncthreads();
  }
  COMPUTE(1);

#undef ISSUE
#undef STAGE
#undef COMPUTE

  const int cr = (lane >> 4) << 2;
  const int cc = lane & 15;
#pragma unroll
  for (int j = 0; j < 4; ++j) {
    const int n = n0 + wn + j * 16 + cc;
    const float bv = bias[n];
#pragma unroll
    for (int i = 0; i < 4; ++i) {
      const int mrow = m0 + wm + i * 16 + cr;
#pragma unroll
      for (int r = 0; r < 4; ++r)
        out[(size_t)(mrow + r) * NDIM + n] = acc[i][j][r] + bv;
    }
  }
}

extern "C" void kernel_launch(void* const* d_in, const int* in_sizes, int n_in,
                              void* d_out, int out_size, void* d_ws, size_t ws_size,
                              hipStream_t stream) {
  const float* A      = (const float*)d_in[0];
  const int*   qwp    = (const int*)d_in[1];
  const float* scales = (const float*)d_in[2];
  const float* zerosp = (const float*)d_in[3];
  const float* biasp  = (const float*)d_in[4];
  float*       outp   = (float*)d_out;

  const size_t needW = (size_t)NDIM * KDIM * sizeof(_Float16);   // 64 MB
  const size_t needA = (size_t)MDIM * KDIM * sizeof(_Float16);   // 16 MB

  if (ws_size >= needW + needA) {
    _Float16* Wf = (_Float16*)d_ws;
    _Float16* Af = (_Float16*)((char*)d_ws + needW);
    dequant_w_kernel<<<2048, 256, 0, stream>>>(qwp, scales, zerosp, Wf);
    conv_a_kernel<<<2048, 256, 0, stream>>>(A, Af);
    dim3 grid(NDIM / 256, MDIM / 256);  // 32 x 8 = 256 blocks (1/CU)
    gemm_f16_kernel<<<grid, 512, 0, stream>>>(Af, Wf, biasp, outp);
  } else {
    dim3 grid(NDIM / 128, MDIM / 128);
    qlin_fused_kernel<<<grid, 256, 0, stream>>>(A, qwp, scales, zerosp, biasp, outp);
  }
}

// Round 17
// 153.632 us; speedup vs baseline: 1.1551x; 1.0128x over previous
//
#include <hip/hip_runtime.h>
#include <stdint.h>

#define MDIM 2048
#define KDIM 4096
#define NDIM 8192
#define NG   32            // K / GROUP_SIZE
#define QROW 2048          // int32 per qweight row
#define NT2  64            // K-tiles of BK=64
#define LSTR 36            // fused-fallback LDS row stride
#define BUFH 32768         // f16 per buffer: A[256][64] + B[256][64]

typedef __attribute__((ext_vector_type(4))) float    f32x4;
typedef __attribute__((ext_vector_type(2))) _Float16 f16x2;
typedef __attribute__((ext_vector_type(8))) _Float16 f16x8;
typedef __attribute__((ext_vector_type(4))) int      i32x4;

#define CVT2(a,b) __builtin_bit_cast(f16x2, __builtin_amdgcn_cvt_pkrtz((a),(b)))
#define BCU(x)    __builtin_bit_cast(unsigned, (x))
#define BCH2(x)   __builtin_bit_cast(f16x2, (x))
#define MFMA16(A,B,C) __builtin_amdgcn_mfma_f32_16x16x32_f16((A),(B),(C),0,0,0)
#define LDSREAD(DST, OFF) __builtin_memcpy(&(DST), &lds[(OFF)], 16)

__device__ __forceinline__ void gload_lds16(const void* g, void* l) {
  __builtin_amdgcn_global_load_lds(
      (const __attribute__((address_space(1))) void*)g,
      (__attribute__((address_space(3))) void*)l, 16, 0, 0);
}

// dequant 4 int32 (8 weights, identity k-order) -> 8 fp16 (verified r3..r16)
__device__ __forceinline__ uint4 dequant8(i32x4 q, float sf, float zf) {
  const _Float16 sh = (_Float16)sf;
  const _Float16 bh = (_Float16)(-zf * sf);
  const f16x2 s2 = {sh, sh}, b2 = {bh, bh};
  const f16x2 k2 = {(_Float16)1024.0f, (_Float16)1024.0f};
  uint4 r;
#define DQE(QV, DST) do {                                                   \
    unsigned Bb_ = (unsigned)(QV) & 0xFFu;                                  \
    unsigned bits_ = ((Bb_ | (Bb_ << 12)) & 0x000F000Fu) | 0x64006400u;     \
    DST = BCU((f16x2)((BCH2(bits_) - k2) * s2 + b2));                       \
  } while (0)
  DQE(q.x, r.x); DQE(q.y, r.y); DQE(q.z, r.z); DQE(q.w, r.w);
#undef DQE
  return r;
}

// ============ pass 1a: W dequant -> f16 [N][K] in ws ============
__global__ __launch_bounds__(256) void dequant_w_kernel(
    const int* __restrict__ qw, const float* __restrict__ scales,
    const float* __restrict__ zeros, _Float16* __restrict__ Wf)
{
  const size_t total = (size_t)NDIM * (KDIM / 8);
  for (size_t t = (size_t)blockIdx.x * blockDim.x + threadIdx.x; t < total;
       t += (size_t)gridDim.x * blockDim.x) {
    i32x4 q;
    __builtin_memcpy(&q, qw + 4 * t, 16);
    const int n = (int)(t >> 9);
    const int k = (int)((t & 511) << 3);
    const int g = k >> 7;
    uint4 w = dequant8(q, scales[n * NG + g], zeros[n * NG + g]);
    __builtin_memcpy(Wf + (size_t)n * KDIM + k, &w, 16);
  }
}

// ============ pass 1b: A f32 -> f16 [M][K] in ws ============
__global__ __launch_bounds__(256) void conv_a_kernel(
    const float* __restrict__ A, _Float16* __restrict__ Af)
{
  const size_t total = (size_t)MDIM * (KDIM / 8);
  for (size_t t = (size_t)blockIdx.x * blockDim.x + threadIdx.x; t < total;
       t += (size_t)gridDim.x * blockDim.x) {
    f32x4 v0, v1;
    __builtin_memcpy(&v0, A + 8 * t,     16);
    __builtin_memcpy(&v1, A + 8 * t + 4, 16);
    uint4 h;
    h.x = BCU(CVT2(v0.x, v0.y));
    h.y = BCU(CVT2(v0.z, v0.w));
    h.z = BCU(CVT2(v1.x, v1.y));
    h.w = BCU(CVT2(v1.z, v1.w));
    __builtin_memcpy(Af + 8 * t, &h, 16);
  }
}

// ============ pass 2: f16 GEMM, 256x256, BK=64, 8 waves, barrier-thinned phases ============
// r16 skeleton (verified PASS, 1023 TF): 2 x 64KB bufs, staging swizzle
// schunk=(t&7)^((t>>3)&7), read chunk=(kk*4+h)^(fr&7) (0 conflicts), spread
// staging 2 gloads/phase, vmcnt(2) gate.
// NEW: only the 2 CORRECTNESS barriers per iter retained (top gate; P3
// pre-stage fence). The 7 alignment-only barriers removed -> waves drift
// within the iteration, so one wave's ds_read drain hides under another
// wave's MFMA cluster (m114 co-scheduling).
__global__ __launch_bounds__(512) void gemm_f16_kernel(
    const _Float16* __restrict__ Af,   // [M][K]
    const _Float16* __restrict__ Wf,   // [N][K]
    const float* __restrict__ bias,    // [N]
    float* __restrict__ out)           // [M][N] f32
{
  __shared__ __align__(16) _Float16 lds[2 * BUFH];   // 128 KB

  const int tid  = threadIdx.x;
  const int wave = tid >> 6;
  const int lane = tid & 63;
  const int n0 = blockIdx.x << 8;
  const int m0 = blockIdx.y << 8;
  const int wm = (wave >> 2) << 7;   // 0 or 128
  const int wn = (wave & 3) << 6;    // 0,64,128,192

  f32x4 acc[8][4] = {};

  // ---- staging (r14/r16 verbatim) ----
  const int srow   = tid >> 3;                      // 0..63
  const int schunk = (tid & 7) ^ ((tid >> 3) & 7);
  const _Float16* aU0 = Af + (size_t)(m0 + srow) * KDIM + schunk * 8;
  const _Float16* aU1 = aU0 + (size_t)64 * KDIM;
  const _Float16* aU2 = aU0 + (size_t)128 * KDIM;
  const _Float16* aU3 = aU0 + (size_t)192 * KDIM;
  const _Float16* bU0 = Wf + (size_t)(n0 + srow) * KDIM + schunk * 8;
  const _Float16* bU1 = bU0 + (size_t)64 * KDIM;
  const _Float16* bU2 = bU0 + (size_t)128 * KDIM;
  const _Float16* bU3 = bU0 + (size_t)192 * KDIM;

#define STAGE_P1(X) do {                                               \
    _Float16* d_ = &lds[((X) & 1) * BUFH + (wave << 9)];               \
    const size_t ko_ = (size_t)(X) << 6;                               \
    gload_lds16(aU0 + ko_, d_);                                        \
    gload_lds16(aU1 + ko_, d_ + 4096);                                 \
  } while (0)
#define STAGE_P2(X) do {                                               \
    _Float16* d_ = &lds[((X) & 1) * BUFH + (wave << 9)];               \
    const size_t ko_ = (size_t)(X) << 6;                               \
    gload_lds16(aU2 + ko_, d_ + 8192);                                 \
    gload_lds16(aU3 + ko_, d_ + 12288);                                \
  } while (0)
#define STAGE_P3(X) do {                                               \
    _Float16* d_ = &lds[((X) & 1) * BUFH + (wave << 9)];               \
    const size_t ko_ = (size_t)(X) << 6;                               \
    gload_lds16(bU0 + ko_, d_ + 16384);                                \
    gload_lds16(bU1 + ko_, d_ + 20480);                                \
  } while (0)
#define STAGE_P4(X) do {                                               \
    _Float16* d_ = &lds[((X) & 1) * BUFH + (wave << 9)];               \
    const size_t ko_ = (size_t)(X) << 6;                               \
    gload_lds16(bU2 + ko_, d_ + 24576);                                \
    gload_lds16(bU3 + ko_, d_ + 28672);                                \
  } while (0)

  // ---- fragment read offsets (r14/r16 verbatim; measured 0 conflicts) ----
  const int fr = lane & 15;
  const int h4 = lane >> 4;
  const int ck0 = (((0 + h4) ^ (fr & 7))) << 3;
  const int ck1 = (((4 + h4) ^ (fr & 7))) << 3;
  int raOff[8], rbOff[4];
#pragma unroll
  for (int i = 0; i < 8; ++i) raOff[i] = (wm + 16 * i + fr) * 64;
#pragma unroll
  for (int j = 0; j < 4; ++j) rbOff[j] = 16384 + (wn + 16 * j + fr) * 64;

  // tail compute (r14/r16 verbatim, no staging)
#define COMPUTE(T) do {                                                \
    const int bb_ = ((T) & 1) * BUFH;                                  \
    f16x8 b0_[4], b1_[4];                                              \
    _Pragma("unroll")                                                  \
    for (int j = 0; j < 4; ++j) {                                      \
      LDSREAD(b0_[j], bb_ + rbOff[j] + ck0);                           \
      LDSREAD(b1_[j], bb_ + rbOff[j] + ck1);                           \
    }                                                                  \
    _Pragma("unroll")                                                  \
    for (int i = 0; i < 8; ++i) {                                      \
      f16x8 a0_, a1_;                                                  \
      LDSREAD(a0_, bb_ + raOff[i] + ck0);                              \
      LDSREAD(a1_, bb_ + raOff[i] + ck1);                              \
      _Pragma("unroll")                                                \
      for (int j = 0; j < 4; ++j)                                      \
        acc[i][j] = MFMA16(a0_, b0_[j], acc[i][j]);                    \
      _Pragma("unroll")                                                \
      for (int j = 0; j < 4; ++j)                                      \
        acc[i][j] = MFMA16(a1_, b1_[j], acc[i][j]);                    \
    }                                                                  \
  } while (0)

  // 16-MFMA phase body (r14/r16 verbatim)
#define PH_MFMA(R) do {                                                \
    __builtin_amdgcn_s_setprio(1);                                     \
    _Pragma("unroll")                                                  \
    for (int j = 0; j < 4; ++j) {                                      \
      acc[(R)][j]     = MFMA16(aA0, bf0[j], acc[(R)][j]);              \
      acc[(R) + 1][j] = MFMA16(aB0, bf0[j], acc[(R) + 1][j]);          \
    }                                                                  \
    _Pragma("unroll")                                                  \
    for (int j = 0; j < 4; ++j) {                                      \
      acc[(R)][j]     = MFMA16(aA1, bf1[j], acc[(R)][j]);              \
      acc[(R) + 1][j] = MFMA16(aB1, bf1[j], acc[(R) + 1][j]);          \
    }                                                                  \
    __builtin_amdgcn_s_setprio(0);                                     \
  } while (0)

#define RD_A(I)                                                        \
    LDSREAD(aA0, bb + raOff[I] + ck0);                                 \
    LDSREAD(aA1, bb + raOff[I] + ck1);                                 \
    LDSREAD(aB0, bb + raOff[(I) + 1] + ck0);                           \
    LDSREAD(aB1, bb + raOff[(I) + 1] + ck1);

  // per-wave read-fence (rule #18: lgkmcnt + sched_barrier, NO s_barrier)
#define RFENCE                                                         \
    asm volatile("s_waitcnt lgkmcnt(0)" ::: "memory");                 \
    __builtin_amdgcn_sched_barrier(0);

  // prologue: tile 0 fully + tile 1 part 1  (10 loads outstanding)
  STAGE_P1(0); STAGE_P2(0); STAGE_P3(0); STAGE_P4(0);
  STAGE_P1(1);

#pragma clang loop unroll(disable)
  for (int t = 0; t < NT2 - 2; ++t) {
    // CORRECTNESS barrier #1: tile t fully landed, all waves see it
    asm volatile("s_waitcnt vmcnt(2)" ::: "memory");
    __builtin_amdgcn_s_barrier();
    const int bb = (t & 1) * BUFH;

    f16x8 bf0[4], bf1[4], aA0, aA1, aB0, aB1;

    // ---- P0: all B frags + A rows 0,1 | stage t+1 part2 ----
#pragma unroll
    for (int j = 0; j < 4; ++j) {
      LDSREAD(bf0[j], bb + rbOff[j] + ck0);
      LDSREAD(bf1[j], bb + rbOff[j] + ck1);
    }
    RD_A(0)
    STAGE_P2(t + 1);
    RFENCE
    PH_MFMA(0);

    // ---- P1: A rows 2,3 | stage t+1 part3 ----
    RD_A(2)
    STAGE_P3(t + 1);
    RFENCE
    PH_MFMA(2);

    // ---- P2: A rows 4,5 | stage t+1 part4 ----
    RD_A(4)
    STAGE_P4(t + 1);
    RFENCE
    PH_MFMA(4);

    // ---- P3: A rows 6,7 | fence | CORRECTNESS barrier #2 | stage t+2 p1 ----
    RD_A(6)
    RFENCE
    __builtin_amdgcn_s_barrier();   // all waves' buf-t reads retired
    STAGE_P1(t + 2);                // overwrites buf t&1 A rows 0-127
    PH_MFMA(6);
  }

  // tail: outstanding = NT2-2 p2,p3,p4 (6, oldest) + NT2-1 p1 (2)
  STAGE_P2(NT2 - 1); STAGE_P3(NT2 - 1); STAGE_P4(NT2 - 1);   // -> 14
  asm volatile("s_waitcnt vmcnt(8)" ::: "memory");            // NT2-2 done
  __builtin_amdgcn_s_barrier();
  COMPUTE(NT2 - 2);
  asm volatile("s_waitcnt vmcnt(0)" ::: "memory");
  __builtin_amdgcn_s_barrier();
  COMPUTE(NT2 - 1);

#undef STAGE_P1
#undef STAGE_P2
#undef STAGE_P3
#undef STAGE_P4
#undef COMPUTE
#undef PH_MFMA
#undef RD_A
#undef RFENCE

  // epilogue: C/D col = lane&15, row = (lane>>4)*4 + reg (r9-r16 verbatim)
  const int cr = (lane >> 4) << 2;
  const int cc = lane & 15;
#pragma unroll
  for (int j = 0; j < 4; ++j) {
    const int n = n0 + wn + j * 16 + cc;
    const float bv = bias[n];
#pragma unroll
    for (int i = 0; i < 8; ++i) {
      const int mrow = m0 + wm + i * 16 + cr;
#pragma unroll
      for (int r = 0; r < 4; ++r)
        out[(size_t)(mrow + r) * NDIM + n] = acc[i][j][r] + bv;
    }
  }
}

// ============ fused fallback (round-6 kernel, verified PASS) ============
__global__ __launch_bounds__(256, 4) void qlin_fused_kernel(
    const float* __restrict__ A, const int* __restrict__ qw,
    const float* __restrict__ scales, const float* __restrict__ zeros,
    const float* __restrict__ bias, float* __restrict__ out)
{
  __shared__ _Float16 As[2][128 * LSTR];
  __shared__ _Float16 Bs[2][128 * LSTR];

  const int tid  = threadIdx.x;
  const int wave = tid >> 6;
  const int lane = tid & 63;
  const int n0 = blockIdx.x << 7;
  const int m0 = blockIdx.y << 7;
  const int wm = (wave >> 1) << 6;
  const int wn = (wave & 1) << 6;

  f32x4 acc[4][4] = {};

  const int r4 = tid >> 2;
  const int c4 = tid & 3;

  const float* aP0 = A + (size_t)(m0 + r4) * KDIM + c4 * 8;
  const float* aP1 = aP0 + (size_t)64 * KDIM;
  const int*   qP0 = qw + (size_t)(n0 + r4) * QROW + c4 * 4;
  const int*   qP1 = qP0 + (size_t)64 * QROW;
  const float* sP0 = scales + (size_t)(n0 + r4) * NG;
  const float* zP0 = zeros  + (size_t)(n0 + r4) * NG;
  const float* sP1 = sP0 + (size_t)64 * NG;
  const float* zP1 = zP0 + (size_t)64 * NG;

  const int aD0 = r4 * LSTR + c4 * 8;
  const int aD1 = (r4 + 64) * LSTR + c4 * 8;

  const int fr = lane & 15;
  const int k0 = (lane >> 4) * 8;
  const int ra0 = (wm +  0 + fr) * LSTR + k0;
  const int ra1 = (wm + 16 + fr) * LSTR + k0;
  const int ra2 = (wm + 32 + fr) * LSTR + k0;
  const int ra3 = (wm + 48 + fr) * LSTR + k0;
  const int rb0 = (wn +  0 + fr) * LSTR + k0;
  const int rb1 = (wn + 16 + fr) * LSTR + k0;
  const int rb2 = (wn + 32 + fr) * LSTR + k0;
  const int rb3 = (wn + 48 + fr) * LSTR + k0;

  f32x4 pa0, pa1, pa2, pa3;
  i32x4 pq0, pq1;
  float psf0, pzf0, psf1, pzf1;

#define ISSUE(KT) do {                                                        \
    __builtin_memcpy(&pa0, aP0 + (size_t)(KT) * 32,     16);                  \
    __builtin_memcpy(&pa1, aP0 + (size_t)(KT) * 32 + 4, 16);                  \
    __builtin_memcpy(&pa2, aP1 + (size_t)(KT) * 32,     16);                  \
    __builtin_memcpy(&pa3, aP1 + (size_t)(KT) * 32 + 4, 16);                  \
    __builtin_memcpy(&pq0, qP0 + (size_t)(KT) * 16, 16);                      \
    __builtin_memcpy(&pq1, qP1 + (size_t)(KT) * 16, 16);                      \
    const int g_ = (KT) >> 2;                                                 \
    psf0 = sP0[g_]; pzf0 = zP0[g_];                                           \
    psf1 = sP1[g_]; pzf1 = zP1[g_];                                           \
  } while (0)

#define STAGE(P) do {                                                         \
    uint4 aw0_;                                                               \
    aw0_.x = BCU(CVT2(pa0.x, pa0.y));                                         \
    aw0_.y = BCU(CVT2(pa0.z, pa0.w));                                         \
    aw0_.z = BCU(CVT2(pa1.x, pa1.y));                                         \
    aw0_.w = BCU(CVT2(pa1.z, pa1.w));                                         \
    __builtin_memcpy(&As[P][aD0], &aw0_, 16);                                 \
    uint4 aw1_;                                                               \
    aw1_.x = BCU(CVT2(pa2.x, pa2.y));                                         \
    aw1_.y = BCU(CVT2(pa2.z, pa2.w));                                         \
    aw1_.z = BCU(CVT2(pa3.x, pa3.y));                                         \
    aw1_.w = BCU(CVT2(pa3.z, pa3.w));                                         \
    __builtin_memcpy(&As[P][aD1], &aw1_, 16);                                 \
    uint4 bw0_ = dequant8(pq0, psf0, pzf0);                                   \
    __builtin_memcpy(&Bs[P][aD0], &bw0_, 16);                                 \
    uint4 bw1_ = dequant8(pq1, psf1, pzf1);                                   \
    __builtin_memcpy(&Bs[P][aD1], &bw1_, 16);                                 \
  } while (0)

#define COMPUTE(P) do {                                                       \
    f16x8 af[4], bfr[4];                                                      \
    __builtin_memcpy(&af[0], &As[P][ra0], 16);                                \
    __builtin_memcpy(&af[1], &As[P][ra1], 16);                                \
    __builtin_memcpy(&af[2], &As[P][ra2], 16);                                \
    __builtin_memcpy(&af[3], &As[P][ra3], 16);                                \
    __builtin_memcpy(&bfr[0], &Bs[P][rb0], 16);                               \
    __builtin_memcpy(&bfr[1], &Bs[P][rb1], 16);                               \
    __builtin_memcpy(&bfr[2], &Bs[P][rb2], 16);                               \
    __builtin_memcpy(&bfr[3], &Bs[P][rb3], 16);                               \
    _Pragma("unroll")                                                         \
    for (int i = 0; i < 4; ++i)                                               \
      _Pragma("unroll")                                                       \
      for (int j = 0; j < 4; ++j)                                             \
        acc[i][j] = MFMA16(af[i], bfr[j], acc[i][j]);                         \
  } while (0)

  ISSUE(0);
  STAGE(0);
  __syncthreads();

#pragma clang loop unroll(disable)
  for (int kt = 0; kt < 127; ++kt) {
    const int p = kt & 1;
    ISSUE(kt + 1);
    COMPUTE(p);
    STAGE(p ^ 1);
    __syncthreads();
  }
  COMPUTE(1);

#undef ISSUE
#undef STAGE
#undef COMPUTE

  const int cr = (lane >> 4) << 2;
  const int cc = lane & 15;
#pragma unroll
  for (int j = 0; j < 4; ++j) {
    const int n = n0 + wn + j * 16 + cc;
    const float bv = bias[n];
#pragma unroll
    for (int i = 0; i < 4; ++i) {
      const int mrow = m0 + wm + i * 16 + cr;
#pragma unroll
      for (int r = 0; r < 4; ++r)
        out[(size_t)(mrow + r) * NDIM + n] = acc[i][j][r] + bv;
    }
  }
}

extern "C" void kernel_launch(void* const* d_in, const int* in_sizes, int n_in,
                              void* d_out, int out_size, void* d_ws, size_t ws_size,
                              hipStream_t stream) {
  const float* A      = (const float*)d_in[0];
  const int*   qwp    = (const int*)d_in[1];
  const float* scales = (const float*)d_in[2];
  const float* zerosp = (const float*)d_in[3];
  const float* biasp  = (const float*)d_in[4];
  float*       outp   = (float*)d_out;

  const size_t needW = (size_t)NDIM * KDIM * sizeof(_Float16);   // 64 MB
  const size_t needA = (size_t)MDIM * KDIM * sizeof(_Float16);   // 16 MB

  if (ws_size >= needW + needA) {
    _Float16* Wf = (_Float16*)d_ws;
    _Float16* Af = (_Float16*)((char*)d_ws + needW);
    dequant_w_kernel<<<2048, 256, 0, stream>>>(qwp, scales, zerosp, Wf);
    conv_a_kernel<<<2048, 256, 0, stream>>>(A, Af);
    dim3 grid(NDIM / 256, MDIM / 256);  // 32 x 8 = 256 blocks (1/CU)
    gemm_f16_kernel<<<grid, 512, 0, stream>>>(Af, Wf, biasp, outp);
  } else {
    dim3 grid(NDIM / 128, MDIM / 128);
    qlin_fused_kernel<<<grid, 256, 0, stream>>>(A, qwp, scales, zerosp, biasp, outp);
  }
}